// Round 2
// baseline (7772.528 us; speedup 1.0000x reference)
//
#include <hip/hip_runtime.h>

#define TT 16384
#define BB 8
#define HH 512
#define CC 24
#define KK 100

// ---------------- GEMM: scoresT[b,c,t] = hs[b,t,:] @ W[:,c] + b[c] ----------------
// One thread per row (B*T rows). Output written TRANSPOSED (B,C,T) so the scan
// kernel can bulk-load each channel's score stream with float4 (t-contiguous).
__global__ __launch_bounds__(256) void score_gemm(
    const float* __restrict__ hs, const float* __restrict__ W,
    const float* __restrict__ bias, float* __restrict__ scoresT) {
  const long row = (long)blockIdx.x * 256 + threadIdx.x;
  const int b = (int)(row >> 14);   // TT = 16384 = 2^14
  const int t = (int)(row & (TT - 1));
  const float* x = hs + row * HH;
  float acc[CC];
#pragma unroll
  for (int c = 0; c < CC; ++c) acc[c] = bias[c];
#pragma unroll 2
  for (int h0 = 0; h0 < HH; h0 += 4) {
    float4 xv = *reinterpret_cast<const float4*>(x + h0);
    const float* wp = W + h0 * CC;
#pragma unroll
    for (int c = 0; c < CC; ++c) acc[c] = fmaf(xv.x, wp[c], acc[c]);
#pragma unroll
    for (int c = 0; c < CC; ++c) acc[c] = fmaf(xv.y, wp[CC + c], acc[c]);
#pragma unroll
    for (int c = 0; c < CC; ++c) acc[c] = fmaf(xv.z, wp[2 * CC + c], acc[c]);
#pragma unroll
    for (int c = 0; c < CC; ++c) acc[c] = fmaf(xv.w, wp[3 * CC + c], acc[c]);
  }
  float* op = scoresT + (long)b * CC * TT + t;
#pragma unroll
  for (int c = 0; c < CC; ++c) op[(long)c * TT] = acc[c];
}

// ---------------- DPP helpers (VALU pipe, no LDS) ----------------
template <int CTRL>
__device__ __forceinline__ float dpp_mov(float x) {
  return __int_as_float(__builtin_amdgcn_update_dpp(
      __float_as_int(x), __float_as_int(x), CTRL, 0xF, 0xF, false));
}
// 0x111 = row_shr:1  (lane l <- lane l-1 within 16-lane row; lane 0 keeps old)
// 0xB1  = quad_perm [1,0,3,2] (xor-1 pair swap)

// ---------------- Streaming semi-Markov CRF scan — SINGLE WAVE per batch ----------------
// 64 lanes; lane pair (2c, 2c+1) owns channel c (c=0..23; lanes 48..63 idle-safe).
//   even lane: taps k=1..50  (E[q] = k-1 = q),      trans rows c'=0..11
//   odd  lane: taps k=51..100 (E[q] = k-1 = q+50),  trans rows c'=12..23
// No __syncthreads anywhere: one wave, LDS ops are in-order within a wave.
// Per step: shift window (rescale folded; boundary tap via DPP row_shr:1),
// 50-tap dot (4 fma chains), pair-sum (DPP xor1) -> alpha; share alpha via LDS,
// 12-wide max tree + pair max -> global am; exp once per lane, share e via LDS,
// 12-fma tree with exp(trans) weights, pair-sum -> msg.
__global__ __launch_bounds__(64) void crf_scan(
    const float* __restrict__ scoresT, const float* __restrict__ trans,
    const float* __restrict__ db, const int* __restrict__ lengths,
    float* __restrict__ out) {
  const int b = blockIdx.x;
  const int lane = threadIdx.x;  // 0..63
  const int c = lane >> 1;       // channel 0..31 (>=24 idle)
  const int par = lane & 1;
  const bool act = (c < CC);
  const int cc = act ? c : 0;

  __shared__ float lds_a[2][32];  // alpha per channel (double-buffered, static addrs)
  __shared__ float lds_e[2][32];  // exp(alpha - am) per channel

  // weights: w[q] = exp(db[k-1, c]), k-1 = par*50 + q  (K=100 splits exactly 50/50)
  float w[50];
  const int kb = par * 50;
#pragma unroll
  for (int q = 0; q < 50; ++q) w[q] = act ? __expf(db[(kb + q) * CC + cc]) : 0.0f;

  // transition coefficients: eT[j] = exp(trans[par*12 + j, c])
  float eT[12];
#pragma unroll
  for (int j = 0; j < 12; ++j)
    eT[j] = act ? __expf(trans[(par * 12 + j) * CC + cc]) : 0.0f;

  int len = lengths[b];
  len = len < 1 ? 1 : (len > TT ? TT : len);

  float E[50];
#pragma unroll
  for (int q = 0; q < 50; ++q) E[q] = 0.0f;

  float cum = 0.0f;     // running cum[t][c] (redundant in pair)
  float u_prev = 0.0f;  // u[0] = msg[0] - cum[0] = 0
  float M = -30.0f;     // current window scale

  const float4* sp4 =
      reinterpret_cast<const float4*>(scoresT + ((long)b * CC + cc) * TT);
  float4 buf0 = sp4[0];
  float4 buf1 = sp4[1];
  const int NJ = TT / 4;

  for (int j = 0; j < NJ; ++j) {
    int jn = j + 2;
    jn = jn < NJ ? jn : NJ - 1;
    float4 nb = sp4[jn];  // 8-step prefetch distance
    float scs[4] = {buf0.x, buf0.y, buf0.z, buf0.w};
#pragma unroll
    for (int u = 0; u < 4; ++u) {
      const int i = 4 * j + u;  // step t = i+1
      cum += scs[u];

      // scale tracking; rescale folded into window shift
      float Mn = fmaxf(M - 0.015625f, u_prev - 30.0f);
      float r = __expf(M - Mn);
      float enew = __expf(u_prev - Mn);
      float tmp = dpp_mov<0x111>(E[49]);  // even lane's k=50 tap -> odd lane's k=51 slot
      M = Mn;
#pragma unroll
      for (int q = 49; q >= 1; --q) E[q] = E[q - 1] * r;
      E[0] = (par == 0) ? enew : tmp * r;

      // 50-tap dot, 4 parallel fma chains
      float s0 = E[0] * w[0], s1 = E[1] * w[1], s2 = E[2] * w[2], s3 = E[3] * w[3];
#pragma unroll
      for (int q = 4; q < 48; q += 4) {
        s0 = fmaf(E[q], w[q], s0);
        s1 = fmaf(E[q + 1], w[q + 1], s1);
        s2 = fmaf(E[q + 2], w[q + 2], s2);
        s3 = fmaf(E[q + 3], w[q + 3], s3);
      }
      s0 = fmaf(E[48], w[48], s0);
      s1 = fmaf(E[49], w[49], s1);
      float s = (s0 + s1) + (s2 + s3);
      s += dpp_mov<0xB1>(s);  // pair sum -> full 100-tap sum, both lanes
      float alpha = cum + M + __logf(s);

      // ---- cross-channel exchange, wave-synchronous (no barrier) ----
      const int bs = u & 1;  // compile-time per unrolled sub-step
      if (par == 0 && act) lds_a[bs][c] = alpha;
      __builtin_amdgcn_wave_barrier();  // compiler fence; HW DS pipe is in-order per wave
      const float4* pa = reinterpret_cast<const float4*>(lds_a[bs]) + par * 3;
      float4 a0 = pa[0], a1 = pa[1], a2 = pa[2];  // 12 alphas (broadcast reads)
      float mx = fmaxf(fmaxf(fmaxf(a0.x, a0.y), fmaxf(a0.z, a0.w)),
                       fmaxf(fmaxf(fmaxf(a1.x, a1.y), fmaxf(a1.z, a1.w)),
                             fmaxf(fmaxf(a2.x, a2.y), fmaxf(a2.z, a2.w))));
      float am = fmaxf(mx, dpp_mov<0xB1>(mx));  // global max over 24 channels

      float e = __expf(alpha - am);  // own channel's exp (both pair lanes)
      if (par == 0 && act) lds_e[bs][c] = e;
      __builtin_amdgcn_wave_barrier();
      const float4* pe = reinterpret_cast<const float4*>(lds_e[bs]) + par * 3;
      float4 e0 = pe[0], e1 = pe[1], e2 = pe[2];

      // msg_c = am + log( sum_{c'} e[c'] * exp(trans[c',c]) ), 12 terms/lane
      float S0 = e0.x * eT[0];
      float S1 = e0.y * eT[1];
      float S2 = e0.z * eT[2];
      float S3 = e0.w * eT[3];
      S0 = fmaf(e1.x, eT[4], S0);
      S1 = fmaf(e1.y, eT[5], S1);
      S2 = fmaf(e1.z, eT[6], S2);
      S3 = fmaf(e1.w, eT[7], S3);
      S0 = fmaf(e2.x, eT[8], S0);
      S1 = fmaf(e2.y, eT[9], S1);
      S2 = fmaf(e2.z, eT[10], S2);
      S3 = fmaf(e2.w, eT[11], S3);
      float S = (S0 + S1) + (S2 + S3);
      S += dpp_mov<0xB1>(S);  // pair sum -> all 24 c'
      float msg = am + __logf(S);
      u_prev = msg - cum;

      if (i == len - 1) {  // partition_b = am + log(sum_c e_c); uniform branch
        float se = ((e0.x + e0.y) + (e0.z + e0.w)) +
                   ((e1.x + e1.y) + (e1.z + e1.w)) +
                   ((e2.x + e2.y) + (e2.z + e2.w));
        se += dpp_mov<0xB1>(se);
        if (lane == 0) out[b] = am + __logf(se);
        return;
      }
    }
    buf0 = buf1;
    buf1 = nb;
  }
}

extern "C" void kernel_launch(void* const* d_in, const int* in_sizes, int n_in,
                              void* d_out, int out_size, void* d_ws, size_t ws_size,
                              hipStream_t stream) {
  const float* hs = (const float*)d_in[0];       // (B,T,H) f32
  const float* W = (const float*)d_in[1];        // (H,C) f32
  const float* bias = (const float*)d_in[2];     // (C,) f32
  const float* trans = (const float*)d_in[3];    // (C,C) f32
  const float* db = (const float*)d_in[4];       // (K,C) f32
  const int* lengths = (const int*)d_in[5];      // (B,) i32
  float* scoresT = (float*)d_ws;                 // (B,C,T) f32 = 12.6 MB scratch

  score_gemm<<<(BB * TT) / 256, 256, 0, stream>>>(hs, W, bias, scoresT);
  crf_scan<<<BB, 64, 0, stream>>>(scoresT, trans, db, lengths, (float*)d_out);
}

// Round 3
// 5934.575 us; speedup vs baseline: 1.3097x; 1.3097x over previous
//
#include <hip/hip_runtime.h>

#define TT 16384
#define BB 8
#define HH 512
#define CC 24
#define KK 100

// ---------------- GEMM: scoresT[b,c,t] = hs[b,t,:] @ W[:,c] + b[c] ----------------
__global__ __launch_bounds__(256) void score_gemm(
    const float* __restrict__ hs, const float* __restrict__ W,
    const float* __restrict__ bias, float* __restrict__ scoresT) {
  const long row = (long)blockIdx.x * 256 + threadIdx.x;
  const int b = (int)(row >> 14);   // TT = 16384 = 2^14
  const int t = (int)(row & (TT - 1));
  const float* x = hs + row * HH;
  float acc[CC];
#pragma unroll
  for (int c = 0; c < CC; ++c) acc[c] = bias[c];
#pragma unroll 2
  for (int h0 = 0; h0 < HH; h0 += 4) {
    float4 xv = *reinterpret_cast<const float4*>(x + h0);
    const float* wp = W + h0 * CC;
#pragma unroll
    for (int c = 0; c < CC; ++c) acc[c] = fmaf(xv.x, wp[c], acc[c]);
#pragma unroll
    for (int c = 0; c < CC; ++c) acc[c] = fmaf(xv.y, wp[CC + c], acc[c]);
#pragma unroll
    for (int c = 0; c < CC; ++c) acc[c] = fmaf(xv.z, wp[2 * CC + c], acc[c]);
#pragma unroll
    for (int c = 0; c < CC; ++c) acc[c] = fmaf(xv.w, wp[3 * CC + c], acc[c]);
  }
  float* op = scoresT + (long)b * CC * TT + t;
#pragma unroll
  for (int c = 0; c < CC; ++c) op[(long)c * TT] = acc[c];
}

// ---------------- DPP helpers (VALU pipe) ----------------
// 0x111 = row_shr:1 (lane l <- lane l-1 in 16-lane row); 0xB1 = quad_perm [1,0,3,2]
template <int CTRL>
__device__ __forceinline__ float dpp_mov(float x) {
  return __int_as_float(__builtin_amdgcn_update_dpp(
      __float_as_int(x), __float_as_int(x), CTRL, 0xF, 0xF, false));
}

// ---------------- Streaming semi-Markov CRF scan — exp-domain chain ----------------
// One wave per batch. Lane pair (2c,2c+1) owns channel c; even lane: taps k=1..50,
// trans rows 0..11; odd lane: taps k=51..100, trans rows 12..23.
// Exp-domain recurrence: enew = S_prev*f, e = s*g with f,g = exp(lagged scales) computed
// OFF the critical chain; global scale P = lagged max-alpha recovered from the e-array
// (am = P + log(max e)) so there is NO alpha exchange. M is piecewise-constant per
// 4-step macro-iteration: taps are statically re-indexed inside the unrolled body
// (E_old[q], X[m]) and rotated+rescaled once per macro (boundary via 4 DPP row_shr:1).
// Critical path/step: S -> mul f -> fma w0 -> DPP pair-sum -> mul g -> e
//                    -> (LDS write + 3x b128 read) -> 3-deep fma tree -> DPP -> S.
__global__ __launch_bounds__(64) void crf_scan(
    const float* __restrict__ scoresT, const float* __restrict__ trans,
    const float* __restrict__ db, const int* __restrict__ lengths,
    float* __restrict__ out) {
  const int b = blockIdx.x;
  const int lane = threadIdx.x;  // 0..63
  const int c = lane >> 1;       // channel (>=24 idle)
  const int par = lane & 1;
  const bool act = (c < CC);
  const int cc = act ? c : 0;

  __shared__ float lds_e[32];  // e_c = exp(alpha_c - P) per channel (single buffer)

  // duration weights: w[q] = exp(db[par*50 + q][c])  (k-1 = par*50+q)
  float w[50];
  const int kb = par * 50;
#pragma unroll
  for (int q = 0; q < 50; ++q) w[q] = act ? __expf(db[(kb + q) * CC + cc]) : 0.0f;
  const float w0e = (par == 0) ? w[0] : 0.0f;  // even lane's k=1 weight
  const float w0o = (par == 1) ? w[0] : 0.0f;  // odd lane's k=51 weight (for X[u] term)

  float eT[12];
#pragma unroll
  for (int q = 0; q < 12; ++q)
    eT[q] = act ? __expf(trans[(par * 12 + q) * CC + cc]) : 0.0f;

  int len = lengths[b];
  len = len < 1 ? 1 : (len > TT ? TT : len);

  // Window state (scale M, fixed within a macro-iter):
  // even: E[q] = scaled exp(u_{i0-2-q}) (tap age q+u+2);  odd: E[q] = u_{i0-52-q}.
  // X[m]: even = enew born at sub-step m (u_{i0+m-1}); odd = boundary taps B[m]=u_{i0+m-51}.
  float E[49], X[4];
#pragma unroll
  for (int q = 0; q < 49; ++q) E[q] = 0.0f;
#pragma unroll
  for (int m = 0; m < 4; ++m) X[m] = 0.0f;

  float cum = 0.0f;    // running per-channel cum (pair-redundant)
  float M = -30.0f;    // window scale (piecewise constant)
  float S = 1.0f;      // matvec result of previous step (chain carrier); S_{-1}:=1 with P=0
  float P0 = 0.0f, P1 = 0.0f, Pprev = 0.0f;  // lagged global scales: P_i = am_{i-2}
  float Pu2 = 0.0f, S2s = 1.0f, cum2s = 0.0f;  // saved at sub-step 2 for u_lag

  const float4* sp4 =
      reinterpret_cast<const float4*>(scoresT + ((long)b * CC + cc) * TT);
  float4 buf0 = sp4[0];
  float4 buf1 = sp4[1];
  const int NJ = TT / 4;
  const float4* pe = reinterpret_cast<const float4*>(lds_e) + par * 3;

  for (int j = 0; j < NJ; ++j) {
    int jn = j + 2;
    jn = jn < NJ ? jn : NJ - 1;
    float4 nb = sp4[jn];  // 8-step prefetch distance
    float scs[4] = {buf0.x, buf0.y, buf0.z, buf0.w};
#pragma unroll
    for (int u = 0; u < 4; ++u) {
      const float P_used = P0;
      // off-chain scale factors (inputs are lagged / already known)
      float f = __expf(fminf(Pprev - cum - M, 80.0f));  // cum here = cum_{i-1}
      cum += scs[u];
      float g = __expf(fminf(cum + M - P_used, 80.0f));

      // window dot, all off-chain except the final enew*w0 fma:
      float ch[4] = {0.0f, 0.0f, 0.0f, 0.0f};
#pragma unroll
      for (int q = 0; q <= 48 - u; ++q)
        ch[q & 3] = fmaf(E[q], w[u + 1 + q], ch[q & 3]);
#pragma unroll
      for (int m = 0; m <= u; ++m)  // X taps; m==u term: odd's B[u] (even: *0)
        ch[m & 3] = fmaf(X[m], (m == u) ? w0o : w[u - m], ch[m & 3]);
      float rest = (ch[0] + ch[1]) + (ch[2] + ch[3]);

      float enew = S * f;                // CHAIN
      float s = fmaf(enew, w0e, rest);   // CHAIN (odd adds 0)
      s += dpp_mov<0xB1>(s);             // CHAIN: pair total = full 100-tap sum
      float e = s * g;                   // CHAIN: e = exp(alpha - P_used)
      X[u] = par ? X[u] : enew;          // off-chain: record newborn tap (even only)

      if (par == 0 && act) lds_e[c] = e;
      __builtin_amdgcn_wave_barrier();   // DS pipe is in-order within a wave
      float4 e0 = pe[0], e1 = pe[1], e2 = pe[2];  // CHAIN: 12 e-values

      // msg matvec: S_c = sum_c' e_c' * exp(trans[c'][c])
      float S0 = e0.x * eT[0], S1 = e0.y * eT[1];
      float S2v = e0.z * eT[2], S3 = e0.w * eT[3];
      S0 = fmaf(e1.x, eT[4], S0);
      S1 = fmaf(e1.y, eT[5], S1);
      S2v = fmaf(e1.z, eT[6], S2v);
      S3 = fmaf(e1.w, eT[7], S3);
      S0 = fmaf(e2.x, eT[8], S0);
      S1 = fmaf(e2.y, eT[9], S1);
      S2v = fmaf(e2.z, eT[10], S2v);
      S3 = fmaf(e2.w, eT[11], S3);
      float Sn = (S0 + S1) + (S2v + S3);
      Sn += dpp_mov<0xB1>(Sn);           // CHAIN: all 24 c'

      // off-chain: exact max-alpha (used as P two steps later)
      float mx = fmaxf(fmaxf(fmaxf(e0.x, e0.y), fmaxf(e0.z, e0.w)),
                       fmaxf(fmaxf(fmaxf(e1.x, e1.y), fmaxf(e1.z, e1.w)),
                             fmaxf(fmaxf(e2.x, e2.y), fmaxf(e2.z, e2.w))));
      mx = fmaxf(mx, dpp_mov<0xB1>(mx));
      float am = P_used + __logf(mx);    // = max_c alpha_c (exact)

      if (4 * j + u == len - 1) {  // partition = P + log(sum_c e_c); uniform branch
        float se = ((e0.x + e0.y) + (e0.z + e0.w)) +
                   ((e1.x + e1.y) + (e1.z + e1.w)) +
                   ((e2.x + e2.y) + (e2.z + e2.w));
        se += dpp_mov<0xB1>(se);
        if (lane == 0) out[b] = P_used + __logf(se);
        return;
      }

      S = Sn;
      Pprev = P_used;
      P0 = P1;
      P1 = am;
      if (u == 2) { Pu2 = P_used; S2s = Sn; cum2s = cum; }
    }

    // ---- macro boundary: M update + rotate/rescale window by 4 taps ----
    float u_lag = Pu2 + __logf(S2s) - cum2s;  // u_{i0+2} (lag-2 at next use)
    float Mn = fmaxf(M - 0.0625f, u_lag - 20.0f);
    float r4 = __expf(M - Mn);
    M = Mn;
    float D0 = dpp_mov<0x111>(E[42]);  // even->odd boundary taps (valid on odd lanes)
    float D1 = dpp_mov<0x111>(E[43]);
    float D2 = dpp_mov<0x111>(E[44]);
    float D3 = dpp_mov<0x111>(E[45]);
#pragma unroll
    for (int q = 48; q >= 4; --q) E[q] = E[q - 4] * r4;
    E[0] = (par ? D0 : X[3]) * r4;
    E[1] = (par ? D1 : X[2]) * r4;
    E[2] = (par ? D2 : X[1]) * r4;
    E[3] = (par ? D3 : X[0]) * r4;
    X[0] = D3 * r4;  // odd's new B[0..3]; even lanes overwrite during sub-steps
    X[1] = D2 * r4;
    X[2] = D1 * r4;
    X[3] = D0 * r4;
    buf0 = buf1;
    buf1 = nb;
  }
}

extern "C" void kernel_launch(void* const* d_in, const int* in_sizes, int n_in,
                              void* d_out, int out_size, void* d_ws, size_t ws_size,
                              hipStream_t stream) {
  const float* hs = (const float*)d_in[0];       // (B,T,H) f32
  const float* W = (const float*)d_in[1];        // (H,C) f32
  const float* bias = (const float*)d_in[2];     // (C,) f32
  const float* trans = (const float*)d_in[3];    // (C,C) f32
  const float* db = (const float*)d_in[4];       // (K,C) f32
  const int* lengths = (const int*)d_in[5];      // (B,) i32
  float* scoresT = (float*)d_ws;                 // (B,C,T) f32 scratch

  score_gemm<<<(BB * TT) / 256, 256, 0, stream>>>(hs, W, bias, scoresT);
  crf_scan<<<BB, 64, 0, stream>>>(scoresT, trans, db, lengths, (float*)d_out);
}